// Round 9
// baseline (376.985 us; speedup 1.0000x reference)
//
#include <hip/hip_runtime.h>
#include <hip/hip_bf16.h>

#define T_TOK 2048
#define DDIM  1024
#define NEXP  8
#define FDIM  4096
#define ROWS  (4096 + 256)

typedef __attribute__((ext_vector_type(8))) short bf16x8;
typedef __attribute__((ext_vector_type(4))) float f32x4;

#define SBW(n) ((((n) >> 3) ^ (n)) & 7)
#define SB0() __builtin_amdgcn_sched_barrier(0)

__device__ __forceinline__ unsigned short f2b(float f) {
  union { float f; unsigned u; } v; v.f = f;
  unsigned r = v.u + 0x7FFF + ((v.u >> 16) & 1);  // RNE
  return (unsigned short)(r >> 16);
}
__device__ __forceinline__ float b2f(unsigned short s) {
  union { unsigned u; float f; } v; v.u = ((unsigned)s) << 16;
  return v.f;
}
__device__ __forceinline__ unsigned cvtpk(float lo, float hi) {
  unsigned r;
  asm("v_cvt_pk_bf16_f32 %0, %1, %2" : "=v"(r) : "v"(lo), "v"(hi));
  return r;
}
__device__ __forceinline__ void gl16(const unsigned short* g, unsigned short* l) {
  __builtin_amdgcn_global_load_lds(
      (const __attribute__((address_space(1))) unsigned int*)(const void*)g,
      (__attribute__((address_space(3))) unsigned int*)(void*)l, 16, 0, 0);
}

// ---------------- router ----------------
__global__ void router_kernel(const float* __restrict__ x, const float* __restrict__ Wr,
                              int* __restrict__ cnt, int* __restrict__ tok,
                              float* __restrict__ prb) {
  int t = (blockIdx.x * blockDim.x + threadIdx.x) >> 6;
  int lane = threadIdx.x & 63;
  if (t >= T_TOK) return;
  const float* xr = x + (size_t)t * DDIM;
  float acc[NEXP];
#pragma unroll
  for (int e = 0; e < NEXP; ++e) acc[e] = 0.f;
#pragma unroll
  for (int i = 0; i < 4; ++i) {
    int d0 = lane * 16 + i * 4;
    float4 xv = *reinterpret_cast<const float4*>(xr + d0);
#pragma unroll
    for (int j = 0; j < 4; ++j) {
      float xd = (&xv.x)[j];
      float4 w0 = *reinterpret_cast<const float4*>(Wr + (size_t)(d0 + j) * NEXP);
      float4 w1 = *reinterpret_cast<const float4*>(Wr + (size_t)(d0 + j) * NEXP + 4);
      acc[0] += xd * w0.x; acc[1] += xd * w0.y; acc[2] += xd * w0.z; acc[3] += xd * w0.w;
      acc[4] += xd * w1.x; acc[5] += xd * w1.y; acc[6] += xd * w1.z; acc[7] += xd * w1.w;
    }
  }
#pragma unroll
  for (int off = 32; off >= 1; off >>= 1)
#pragma unroll
    for (int e = 0; e < NEXP; ++e) acc[e] += __shfl_down(acc[e], off);
  if (lane == 0) {
    float v0 = -1e30f, v1 = -1e30f; int i0 = 0, i1 = 0;
#pragma unroll
    for (int e = 0; e < NEXP; ++e) {
      float v = acc[e];
      if (v > v0)      { v1 = v0; i1 = i0; v0 = v; i0 = e; }
      else if (v > v1) { v1 = v; i1 = e; }
    }
    float e1 = __expf(v1 - v0);
    float p0 = 1.f / (1.f + e1);
    float p1 = e1 * p0;
    int s0 = atomicAdd(&cnt[i0], 1);
    tok[i0 * T_TOK + s0] = t; prb[i0 * T_TOK + s0] = p0;
    int s1 = atomicAdd(&cnt[i1], 1);
    tok[i1 * T_TOK + s1] = t; prb[i1 * T_TOK + s1] = p1;
  }
}

// ---------------- x fp32 -> bf16 ----------------
__global__ void cvt_x_kernel(const float* __restrict__ in, unsigned short* __restrict__ o) {
  size_t i = ((size_t)blockIdx.x * 256 + threadIdx.x) * 8;
  float4 a = *reinterpret_cast<const float4*>(in + i);
  float4 b = *reinterpret_cast<const float4*>(in + i + 4);
  bf16x8 p;
  p[0] = (short)f2b(a.x); p[1] = (short)f2b(a.y); p[2] = (short)f2b(a.z); p[3] = (short)f2b(a.w);
  p[4] = (short)f2b(b.x); p[5] = (short)f2b(b.y); p[6] = (short)f2b(b.z); p[7] = (short)f2b(b.w);
  *reinterpret_cast<bf16x8*>(o + i) = p;
}

// =====================================================================
// Kernel F: W1/W3 panel (1024k x 64n each) stationary in registers.
// 8 waves: w0-3 hold W1 frags (h), w4-7 hold W3 frags (g). Streams the
// expert's token rows in 16-row chunks; silu(h)*g fused via LDS bounce.
// =====================================================================
__global__ __launch_bounds__(512, 2)
void moe_ffn1_kernel(const unsigned short* __restrict__ xb,
                     const float* __restrict__ W1, const float* __restrict__ W3,
                     const int* __restrict__ cnt, const int* __restrict__ tok,
                     unsigned short* __restrict__ act) {
  const int e = blockIdx.z;
  const int cn = cnt[e];
  if (cn <= 0) return;
  const int n0 = blockIdx.x * 64;
  int off = 0;
#pragma unroll
  for (int i = 0; i < NEXP; ++i) off += (i < e) ? cnt[i] : 0;

  __shared__ __align__(16) unsigned short sA[2][16 * 1024];  // 64 KB (chunk dbuf / startup slabs)
  __shared__ __align__(16) unsigned short sbounce[4 * 256];  // 2 KB

  const int tid = threadIdx.x;
  const int lane = tid & 63;
  const int w = tid >> 6;

  // ---------- startup: W panel -> 32 register B-frags ----------
  bf16x8 wf[32];
  {
    const int kq = w;                    // 8 k-rows per wave-group
    const int vn = (tid & 63) * 2;       // virtual col 0,2,...,126 (0-63 W1, 64-127 W3)
    const float* bp0 = ((vn < 64) ? W1 : W3)
                     + (size_t)e * DDIM * FDIM + n0 + (vn & 63);
    const int vw = w * 16 + (lane & 15);
    const int sbv = SBW(vw);
    float2 br2[8];
#define LOADSLAB(S)                                                           \
    _Pragma("unroll") for (int r = 0; r < 8; ++r)                             \
      br2[r] = *reinterpret_cast<const float2*>(                              \
          bp0 + (size_t)((S) * 64 + kq * 8 + r) * FDIM);
    LOADSLAB(0);
#pragma unroll
    for (int s = 0; s < 16; ++s) {
      unsigned short* slab = &sA[s & 1][0];
#pragma unroll
      for (int c = 0; c < 2; ++c) {
        union { bf16x8 v; unsigned u[4]; } p;
        p.u[0] = cvtpk((&br2[0].x)[c], (&br2[1].x)[c]);
        p.u[1] = cvtpk((&br2[2].x)[c], (&br2[3].x)[c]);
        p.u[2] = cvtpk((&br2[4].x)[c], (&br2[5].x)[c]);
        p.u[3] = cvtpk((&br2[6].x)[c], (&br2[7].x)[c]);
        *reinterpret_cast<bf16x8*>(&slab[(vn + c) * 64 + ((kq ^ SBW(vn + c)) * 8)]) = p.v;
      }
      if (s < 15) LOADSLAB(s + 1);
      SB0(); asm volatile("s_waitcnt lgkmcnt(0)" ::: "memory");
      __builtin_amdgcn_s_barrier(); SB0();
#pragma unroll
      for (int t = 0; t < 2; ++t)
        wf[2 * s + t] = *reinterpret_cast<const bf16x8*>(
            &slab[vw * 64 + (((t * 4 + (lane >> 4)) ^ sbv) * 8)]);
      // drain the wf ds_reads BEFORE the barrier: other waves overwrite this
      // slab buffer at s+2 and s_barrier does not order LDS data return.
      SB0(); asm volatile("s_waitcnt lgkmcnt(0)" ::: "memory");
      __builtin_amdgcn_s_barrier(); SB0();
    }
#undef LOADSLAB
  }

  // ---------- chunk stream ----------
  const int nch = (cn + 15) >> 4;
  const int sslot = (w & 1) * 64 + lane;

#define STAGE_F(CS, BUF)                                                       \
  _Pragma("unroll") for (int g = 0; g < 4; ++g) {                              \
    int r = g * 4 + (w >> 1);                                                  \
    int slot = (CS) * 16 + r; if (slot >= cn) slot = cn - 1;                   \
    int tk = tok[e * T_TOK + slot];                                            \
    const unsigned short* src = xb + (size_t)tk * DDIM + ((sslot ^ (r & 7)) * 8); \
    gl16(src, &sA[BUF][(g * 8 + w) * 512]);                                    \
  }

  STAGE_F(0, 0);
  SB0(); asm volatile("s_waitcnt vmcnt(0) lgkmcnt(0)" ::: "memory");
  __builtin_amdgcn_s_barrier(); SB0();

  const int mycol = n0 + (w & 3) * 16 + (lane & 15);
  const int arow = (lane & 15) * 1024;
  const int axor = lane & 7;
  const int aq = lane >> 4;

  int cur = 0;
  for (int c = 0; c < nch; ++c, cur ^= 1) {
    int cs = c + 1; if (cs >= nch) cs = nch - 1;
    STAGE_F(cs, cur ^ 1);

    f32x4 acc = (f32x4){0.f, 0.f, 0.f, 0.f};
    {
      const unsigned short* ap = &sA[cur][0];
      __builtin_amdgcn_s_setprio(1);
#pragma unroll
      for (int ks = 0; ks < 32; ++ks) {
        bf16x8 a = *reinterpret_cast<const bf16x8*>(
            &ap[arow + (((ks * 4 + aq) ^ axor) * 8)]);
        acc = __builtin_amdgcn_mfma_f32_16x16x32_bf16(a, wf[ks], acc, 0, 0, 0);
      }
      __builtin_amdgcn_s_setprio(0);
    }

    // epilogue: g-waves publish, h-waves combine+store
    if (w >= 4) {
      unsigned q0 = cvtpk(acc[0], acc[1]);
      unsigned q1 = cvtpk(acc[2], acc[3]);
      *reinterpret_cast<uint2*>(reinterpret_cast<char*>(sbounce)
          + (w - 4) * 512 + (lane & 15) * 32 + (lane >> 4) * 8) = (uint2){q0, q1};
    }
    SB0(); asm volatile("s_waitcnt lgkmcnt(0)" ::: "memory");
    __builtin_amdgcn_s_barrier(); SB0();
    if (w < 4) {
      uint2 gv = *reinterpret_cast<const uint2*>(reinterpret_cast<const char*>(sbounce)
          + w * 512 + (lane & 15) * 32 + (lane >> 4) * 8);
#pragma unroll
      for (int j = 0; j < 4; ++j) {
        int s = c * 16 + (lane >> 4) * 4 + j;
        if (s < cn) {
          float h = acc[j];
          unsigned short gu = (unsigned short)((j < 2 ? gv.x : gv.y) >> ((j & 1) * 16));
          float gvf = b2f(gu);
          float sg = h / (1.f + __expf(-h));
          act[(size_t)(off + s) * FDIM + mycol] = f2b(sg * gvf);
        }
      }
      // drain tok+gl16 (older), keep the 4 stores in flight
      SB0(); asm volatile("s_waitcnt vmcnt(4) lgkmcnt(0)" ::: "memory");
    } else {
      SB0(); asm volatile("s_waitcnt vmcnt(0) lgkmcnt(0)" ::: "memory");
    }
    __builtin_amdgcn_s_barrier(); SB0();
  }
#undef STAGE_F
}

// =====================================================================
// Kernel 2: W2 slice (1024k x 128n, split-K=4) stationary in registers.
// Streams act rows in 16-row chunks; atomic scatter epilogue.
// =====================================================================
__global__ __launch_bounds__(512, 2)
void moe_ffn2_kernel(const unsigned short* __restrict__ actv, const float* __restrict__ W2,
                     const int* __restrict__ cnt, const int* __restrict__ tok,
                     const float* __restrict__ prb, float* __restrict__ out) {
  const int e = blockIdx.z;
  const int sp = blockIdx.y;
  const int cn = cnt[e];
  if (cn <= 0) return;
  const int n0 = blockIdx.x * 128;
  const int kbase = sp * 1024;
  int off = 0;
#pragma unroll
  for (int i = 0; i < NEXP; ++i) off += (i < e) ? cnt[i] : 0;

  __shared__ __align__(16) unsigned short sA[2][16 * 1024];  // 64 KB

  const int tid = threadIdx.x;
  const int lane = tid & 63;
  const int w = tid >> 6;

  // ---------- startup: W2 slice -> 32 register B-frags ----------
  bf16x8 wf[32];
  {
    const int kq = w;
    const int vn = (tid & 63) * 2;       // col 0,2,...,126
    const float* bp0 = W2 + (size_t)e * FDIM * DDIM + (size_t)kbase * DDIM + n0 + vn;
    const int vw = w * 16 + (lane & 15);
    const int sbv = SBW(vw);
    float2 br2[8];
#define LOADSLAB(S)                                                           \
    _Pragma("unroll") for (int r = 0; r < 8; ++r)                             \
      br2[r] = *reinterpret_cast<const float2*>(                              \
          bp0 + (size_t)((S) * 64 + kq * 8 + r) * DDIM);
    LOADSLAB(0);
#pragma unroll
    for (int s = 0; s < 16; ++s) {
      unsigned short* slab = &sA[s & 1][0];
#pragma unroll
      for (int c = 0; c < 2; ++c) {
        union { bf16x8 v; unsigned u[4]; } p;
        p.u[0] = cvtpk((&br2[0].x)[c], (&br2[1].x)[c]);
        p.u[1] = cvtpk((&br2[2].x)[c], (&br2[3].x)[c]);
        p.u[2] = cvtpk((&br2[4].x)[c], (&br2[5].x)[c]);
        p.u[3] = cvtpk((&br2[6].x)[c], (&br2[7].x)[c]);
        *reinterpret_cast<bf16x8*>(&slab[(vn + c) * 64 + ((kq ^ SBW(vn + c)) * 8)]) = p.v;
      }
      if (s < 15) LOADSLAB(s + 1);
      SB0(); asm volatile("s_waitcnt lgkmcnt(0)" ::: "memory");
      __builtin_amdgcn_s_barrier(); SB0();
#pragma unroll
      for (int t = 0; t < 2; ++t)
        wf[2 * s + t] = *reinterpret_cast<const bf16x8*>(
            &slab[vw * 64 + (((t * 4 + (lane >> 4)) ^ sbv) * 8)]);
      // drain the wf ds_reads BEFORE the barrier (slab reused at s+2)
      SB0(); asm volatile("s_waitcnt lgkmcnt(0)" ::: "memory");
      __builtin_amdgcn_s_barrier(); SB0();
    }
#undef LOADSLAB
  }

  // ---------- chunk stream ----------
  const int nch = (cn + 15) >> 4;
  const int sslot = (w & 1) * 64 + lane;

#define STAGE_K(CS, BUF)                                                       \
  _Pragma("unroll") for (int g = 0; g < 4; ++g) {                              \
    int r = g * 4 + (w >> 1);                                                  \
    const unsigned short* src = actv + (size_t)(off + (CS) * 16 + r) * FDIM    \
                              + kbase + ((sslot ^ (r & 7)) * 8);               \
    gl16(src, &sA[BUF][(g * 8 + w) * 512]);                                    \
  }

  STAGE_K(0, 0);
  SB0(); asm volatile("s_waitcnt vmcnt(0) lgkmcnt(0)" ::: "memory");
  __builtin_amdgcn_s_barrier(); SB0();

  const int mycol = n0 + w * 16 + (lane & 15);
  const int arow = (lane & 15) * 1024;
  const int axor = lane & 7;
  const int aq = lane >> 4;

  int cur = 0;
  for (int c = 0; c < nch; ++c, cur ^= 1) {
    int cs = c + 1; if (cs >= nch) cs = nch - 1;
    STAGE_K(cs, cur ^ 1);

    f32x4 acc = (f32x4){0.f, 0.f, 0.f, 0.f};
    {
      const unsigned short* ap = &sA[cur][0];
      __builtin_amdgcn_s_setprio(1);
#pragma unroll
      for (int ks = 0; ks < 32; ++ks) {
        bf16x8 a = *reinterpret_cast<const bf16x8*>(
            &ap[arow + (((ks * 4 + aq) ^ axor) * 8)]);
        acc = __builtin_amdgcn_mfma_f32_16x16x32_bf16(a, wf[ks], acc, 0, 0, 0);
      }
      __builtin_amdgcn_s_setprio(0);
    }

#pragma unroll
    for (int j = 0; j < 4; ++j) {
      int s = c * 16 + (lane >> 4) * 4 + j;
      if (s < cn) {
        int tkn = tok[e * T_TOK + s];
        float p = prb[e * T_TOK + s];
        atomicAdd(&out[(size_t)tkn * DDIM + mycol], p * acc[j]);
      }
    }
    // drain gl16 (older), keep the 4 atomics in flight
    SB0(); asm volatile("s_waitcnt vmcnt(4) lgkmcnt(0)" ::: "memory");
    __builtin_amdgcn_s_barrier(); SB0();
  }
#undef STAGE_K
}

// ============================================================================
extern "C" void kernel_launch(void* const* d_in, const int* in_sizes, int n_in,
                              void* d_out, int out_size, void* d_ws, size_t ws_size,
                              hipStream_t stream) {
  const float* x  = (const float*)d_in[0];
  const float* Wr = (const float*)d_in[1];
  const float* W1 = (const float*)d_in[2];
  const float* W2 = (const float*)d_in[3];
  const float* W3 = (const float*)d_in[4];
  float* out = (float*)d_out;

  char* ws = (char*)d_ws;
  int*   cnt = (int*)ws;                      // 32 B
  int*   tok = (int*)(ws + 1024);             // 64 KB
  float* prb = (float*)(ws + 1024 + 65536);   // 64 KB
  unsigned short* xb  = (unsigned short*)(ws + 256 * 1024);   // 4 MB
  unsigned short* act = xb + (size_t)T_TOK * DDIM;            // ROWS x FDIM bf16

  hipMemsetAsync(cnt, 0, NEXP * sizeof(int), stream);
  hipMemsetAsync(d_out, 0, (size_t)out_size * sizeof(float), stream);

  router_kernel<<<T_TOK / 4, 256, 0, stream>>>(x, Wr, cnt, tok, prb);
  cvt_x_kernel<<<(T_TOK * DDIM) / (256 * 8), 256, 0, stream>>>(x, xb);
  moe_ffn1_kernel<<<dim3(FDIM / 64, 1, NEXP), 512, 0, stream>>>(xb, W1, W3, cnt, tok, act);
  moe_ffn2_kernel<<<dim3(DDIM / 128, 4, NEXP), 512, 0, stream>>>(act, W2, cnt, tok, prb, out);
}